// Round 14
// baseline (57.411 us; speedup 1.0000x reference)
//
#include <hip/hip_runtime.h>
#include <math.h>

#define HOP 128
#define T_LEN 640000
#define N_FRAMES 5001
#define N_PAIRS 2501
#define NB 64
#define GPB 16            // pair-groups per block; 16 threads per group

// LDS geometry (v2f units). Group strides rotate banks.
#define RE_SLOT 18
#define RE_GRP  164       // 9 slots (k=0..8), span 8*18+16=160, pad 164
#define IM_SLOT 18
#define IM_GRP  146       // 8 slots (k=1..8), span 7*18+16=142, pad 146

typedef float v2f __attribute__((ext_vector_type(2)));

static __device__ __forceinline__ v2f mk2(float a, float b) { v2f r; r.x = a; r.y = b; return r; }
static __device__ __forceinline__ v2f sp(float s) { v2f r; r.x = s; r.y = s; return r; }

// 16-lane sum reduction via DPP (no LDS traffic); groups are 16-lane aligned.
static __device__ __forceinline__ float rsum16(float v) {
    v += __int_as_float(__builtin_amdgcn_update_dpp(0, __float_as_int(v), 0xB1, 0xF, 0xF, true));  // quad_perm [1,0,3,2]
    v += __int_as_float(__builtin_amdgcn_update_dpp(0, __float_as_int(v), 0x4E, 0xF, 0xF, true));  // quad_perm [2,3,0,1]
    v += __int_as_float(__builtin_amdgcn_update_dpp(0, __float_as_int(v), 0x141, 0xF, 0xF, true)); // row_half_mirror
    v += __int_as_float(__builtin_amdgcn_update_dpp(0, __float_as_int(v), 0x140, 0xF, 0xF, true)); // row_mirror
    return v;
}

// ws layout (floats): [0..511] twT as 256 v2f (only [16+r] = stp read now)
//                     [512..527] aw8[r]; [528] aw[128]
__global__ __launch_bounds__(256) void setup_kernel(float* __restrict__ ws) {
    __shared__ float s_aw[132];
    const int tid = threadIdx.x;
    const float TP = 0.02454369260617026f; // 2*pi/256
    {
        const int w = tid >> 4, rr = tid & 15;
        float s, c;
        sincosf((float)(rr * w) * TP, &s, &c);
        ((v2f*)ws)[tid] = mk2(c, -s);
    }
    if (tid < 129) {
        const float LG2_10 = 0.30102999566398f; // log10(x) = log2(x)*this
        float fq = (float)tid * 62.5f;
        float f2 = fq * fq;
        const float a0 = 12194.217f * 12194.217f;
        const float a1 = 20.598997f * 20.598997f;
        const float a2 = 107.65265f * 107.65265f;
        const float a3 = 737.86223f * 737.86223f;
        float w = 2.0f + 20.0f * LG2_10 *
                  (__builtin_amdgcn_logf(a0) + 2.0f * __builtin_amdgcn_logf(fmaxf(f2, 1e-30f))
                 - __builtin_amdgcn_logf(f2 + a0) - __builtin_amdgcn_logf(f2 + a1)
                 - 0.5f * __builtin_amdgcn_logf(f2 + a2) - 0.5f * __builtin_amdgcn_logf(f2 + a3));
        s_aw[tid] = fmaxf(w, -80.0f);
    }
    __syncthreads();
    if (tid < 16) {
        float s = 0.f;
#pragma unroll
        for (int k2 = 0; k2 < 8; ++k2) s += s_aw[tid + 16 * k2];
        ws[512 + tid] = s;
        if (tid == 0) ws[528] = s_aw[128];
    }
}

__global__ __launch_bounds__(256) void loudness_kernel(const float* __restrict__ x,
                                                       float* __restrict__ out,
                                                       const float* __restrict__ ws) {
    constexpr float C16[16] = {
        1.0f,  0.9238795325112867f,  0.7071067811865476f,  0.3826834323650898f,
        0.0f, -0.3826834323650898f, -0.7071067811865476f, -0.9238795325112867f,
       -1.0f, -0.9238795325112867f, -0.7071067811865476f, -0.3826834323650898f,
        0.0f,  0.3826834323650898f,  0.7071067811865476f,  0.9238795325112867f};
    constexpr float S16[16] = {
        0.0f,  0.3826834323650898f,  0.7071067811865476f,  0.9238795325112867f,
        1.0f,  0.9238795325112867f,  0.7071067811865476f,  0.3826834323650898f,
        0.0f, -0.3826834323650898f, -0.7071067811865476f, -0.9238795325112867f,
       -1.0f, -0.9238795325112867f, -0.7071067811865476f, -0.3826834323650898f};
    const float R2  = 0.7071067811865476f;
    const float c1v = 0.9238795325112867f, s1v = 0.3826834323650898f;
    const float c3v = 0.3826834323650898f, s3v = 0.9238795325112867f;
    const float CP8 = 0.9238795325112867f, SP8 = 0.3826834323650898f;
    const float K2  = 1.8477590650225735f; // 2*cos(pi/8)

    __shared__ alignas(16) v2f s_re[16 * RE_GRP];  // 20992 B
    __shared__ alignas(16) v2f s_im[16 * IM_GRP];  // 18688 B -> 39680 total (4 blk/CU)

    const int tid = threadIdx.x;
    const int g = tid >> 4;   // pair-group in block (4 groups per wave)
    const int r = tid & 15;   // lane role: stage-1 n1 (writer w=r); stage-2 k1

    // ---- preamble: per-lane scalars only; NO shared tables, NO barrier ----
    const float aw8r  = ws[512 + r];
    const float aw128 = ws[528];
    const v2f stp = ((const v2f*)ws)[16 + r];   // (cos,-sin)(2pi*r/256)

    // Hann window win(n2) = 0.5 - 0.5*cos(th_r + n2*pi/8), hoisted recurrence
    float win16[16];
    {
        float cm2 = stp.x;
        float cm1 = stp.x * CP8 + stp.y * SP8;  // cos(th + pi/8)  (stp.y = -sin th)
        win16[0] = 0.5f - 0.5f * cm2;
        win16[1] = 0.5f - 0.5f * cm1;
#pragma unroll
        for (int n = 2; n < 16; ++n) {
            const float c = K2 * cm1 - cm2;
            win16[n] = 0.5f - 0.5f * c;
            cm2 = cm1; cm1 = c;
        }
    }

    const int gp = blockIdx.x * GPB + g;
    const int b  = gp / N_PAIRS;
    const int pp = gp - b * N_PAIRS;
    const int fA = 2 * pp;
    const int fB = (fA < 5000) ? fA + 1 : 5000;  // last pair duplicates frame 5000
    const int dB = (fB - fA) * HOP;              // 128 or 0
    const float* __restrict__ xb = x + (size_t)b * T_LEN;

    // ---- load + window, frames packed (A,B) in v2f ----
    // Interior: dB==128==16*8, so B's sample n2 == A's sample n2+8 (24 loads).
    v2f xw[16];
    const int base = fA * HOP - HOP + r;
    if (pp >= 1 && pp <= 2499) {
        const float* __restrict__ xp = xb + base;
        float s24[24];
#pragma unroll
        for (int j = 0; j < 24; ++j) s24[j] = xp[16 * j];
#pragma unroll
        for (int n2 = 0; n2 < 16; ++n2)
            xw[n2] = mk2(s24[n2], s24[n2 + 8]) * sp(win16[n2]);
    } else {
#pragma unroll
        for (int n2 = 0; n2 < 16; ++n2) {
            int jA = base + 16 * n2;
            int jB = jA + dB;
            jA = (jA < 0) ? -jA : jA;
            jA = (jA >= T_LEN) ? (2 * T_LEN - 2 - jA) : jA;
            jB = (jB < 0) ? -jB : jB;
            jB = (jB >= T_LEN) ? (2 * T_LEN - 2 - jB) : jB;
            xw[n2] = mk2(xb[jA], xb[jB]) * sp(win16[n2]);
        }
    }

    // ---- stage 1: real DFT-16 over n2 (frames packed), Hermitian compact ----
    v2f pv[8], qv[8];
#pragma unroll
    for (int n = 1; n <= 7; ++n) { pv[n] = xw[n] + xw[16 - n]; qv[n] = xw[n] - xw[16 - n]; }
    const v2f bse = xw[0] + xw[8];
    const v2f d08 = xw[0] - xw[8];
    const v2f se  = pv[2] + pv[4] + pv[6];
    const v2f so  = pv[1] + pv[3] + pv[5] + pv[7];
    const v2f r0  = bse + se + so;
    const v2f r8  = bse + se - so;
    v2f rre[8], rim[8];
#pragma unroll
    for (int k1 = 1; k1 <= 7; ++k1) {
        v2f re = (k1 & 1) ? d08 : bse;
        v2f im = sp(0.f);
#pragma unroll
        for (int n = 1; n <= 7; ++n) {
            const int m = (k1 * n) & 15;
            re += pv[n] * sp(C16[m]);
            im -= qv[n] * sp(S16[m]);
        }
        rre[k1] = re;
        rim[k1] = im;
    }

    // ---- write-side twiddle: Z(k) = raw(k) * e^{-2pi i k r/256}, k=0..8 ----
    // tw recurrence: tw(1)=stp, tw(k+1)=tw(k)*stp (8 complex muls, once).
    {
        v2f* __restrict__ reW = &s_re[g * RE_GRP + r];
        v2f* __restrict__ imW = &s_im[g * IM_GRP + r];
        reW[0] = r0;                   // Z(0) real
        float twx = stp.x, twy = stp.y;
#pragma unroll
        for (int k = 1; k <= 7; ++k) {
            reW[RE_SLOT * k]       = rre[k] * sp(twx) - rim[k] * sp(twy);
            imW[IM_SLOT * (k - 1)] = rre[k] * sp(twy) + rim[k] * sp(twx);
            const float nx = twx * stp.x - twy * stp.y;
            const float ny = twx * stp.y + twy * stp.x;
            twx = nx; twy = ny;
        }
        reW[RE_SLOT * 8] = r8 * sp(twx);   // Z(8) = r8 * tw(8)  (complex!)
        imW[IM_SLOT * 7] = r8 * sp(twy);
    }
    // groups are intra-wave (16 lanes within one wave64): no barrier needed,
    // compiler inserts lgkmcnt for the LDS RAW hazard.

    // ---- read column (transpose, b128 = two w's); twiddle already applied ----
    // r<=8: bb[w] = Z_w(r).  r>8: bb[w] = conj(Z_w(16-r)) * W16^w (const!).
    const int rp  = (r <= 8) ? r : 16 - r;
    const int rpi = (rp >= 1) ? (rp - 1) : 0;      // r=0 -> dummy slot (y0=0)
    const bool lo = (r <= 8);
    const float y0 = (r == 0) ? 0.f : 1.f;
    const float4* __restrict__ reCol = (const float4*)&s_re[g * RE_GRP + RE_SLOT * rp];
    const float4* __restrict__ imCol = (const float4*)&s_im[g * IM_GRP + IM_SLOT * rpi];

    v2f bbx[16], bby[16];
#pragma unroll
    for (int j = 0; j < 8; ++j) {
        const float4 R4v = reCol[j];
        const float4 I4v = imCol[j];
        {
            const int w = 2 * j;
            const float Aw = lo ? 1.f : C16[w];
            const float Bw = lo ? 0.f : S16[w];
            const float Ew = lo ? y0  : -C16[w];
            const v2f Zx = mk2(R4v.x, R4v.y);
            const v2f Zy = mk2(I4v.x, I4v.y);
            bbx[w] = Zx * sp(Aw) - Zy * sp(Bw);
            bby[w] = Zy * sp(Ew) - Zx * sp(Bw);
        }
        {
            const int w = 2 * j + 1;
            const float Aw = lo ? 1.f : C16[w];
            const float Bw = lo ? 0.f : S16[w];
            const float Ew = lo ? y0  : -C16[w];
            const v2f Zx = mk2(R4v.z, R4v.w);
            const v2f Zy = mk2(I4v.z, I4v.w);
            bbx[w] = Zx * sp(Aw) - Zy * sp(Bw);
            bby[w] = Zy * sp(Ew) - Zx * sp(Bw);
        }
    }

    // ---- stage 2: radix-2 DIF FFT-16 over w ----
#pragma unroll
    for (int j = 0; j < 8; ++j) {
        const v2f ux = bbx[j], uy = bby[j], vx = bbx[j + 8], vy = bby[j + 8];
        bbx[j] = ux + vx; bby[j] = uy + vy;
        const v2f dx = ux - vx, dy = uy - vy;
        v2f ox, oy;
        if      (j == 0) { ox = dx;                              oy = dy; }
        else if (j == 1) { ox =  dx * sp(c1v) + dy * sp(s1v);    oy =  dy * sp(c1v) - dx * sp(s1v); }
        else if (j == 2) { ox = (dx + dy) * sp(R2);              oy = (dy - dx) * sp(R2); }
        else if (j == 3) { ox =  dx * sp(c3v) + dy * sp(s3v);    oy =  dy * sp(c3v) - dx * sp(s3v); }
        else if (j == 4) { ox = dy;                              oy = sp(0.f) - dx; }
        else if (j == 5) { ox = dy * sp(s3v) - dx * sp(c3v);     oy = sp(0.f) - dy * sp(c3v) - dx * sp(s3v); }
        else if (j == 6) { ox = (dy - dx) * sp(R2);              oy = sp(0.f) - (dx + dy) * sp(R2); }
        else             { ox = dy * sp(s1v) - dx * sp(c1v);     oy = sp(0.f) - dy * sp(c1v) - dx * sp(s1v); }
        bbx[j + 8] = ox; bby[j + 8] = oy;
    }
#pragma unroll
    for (int h = 0; h <= 8; h += 8) {
#pragma unroll
        for (int j = 0; j < 4; ++j) {
            const v2f ux = bbx[h + j], uy = bby[h + j], vx = bbx[h + j + 4], vy = bby[h + j + 4];
            bbx[h + j] = ux + vx; bby[h + j] = uy + vy;
            const v2f dx = ux - vx, dy = uy - vy;
            v2f ox, oy;
            if      (j == 0) { ox = dx;                  oy = dy; }
            else if (j == 1) { ox = (dx + dy) * sp(R2);  oy = (dy - dx) * sp(R2); }
            else if (j == 2) { ox = dy;                  oy = sp(0.f) - dx; }
            else             { ox = (dy - dx) * sp(R2);  oy = sp(0.f) - (dx + dy) * sp(R2); }
            bbx[h + j + 4] = ox; bby[h + j + 4] = oy;
        }
    }
#pragma unroll
    for (int gg = 0; gg < 16; gg += 4) {
        {
            const v2f ux = bbx[gg], uy = bby[gg], vx = bbx[gg + 2], vy = bby[gg + 2];
            bbx[gg] = ux + vx;     bby[gg] = uy + vy;
            bbx[gg + 2] = ux - vx; bby[gg + 2] = uy - vy;
        }
        {
            const v2f ux = bbx[gg + 1], uy = bby[gg + 1], vx = bbx[gg + 3], vy = bby[gg + 3];
            bbx[gg + 1] = ux + vx; bby[gg + 1] = uy + vy;
            const v2f dx = ux - vx, dy = uy - vy;
            bbx[gg + 3] = dy; bby[gg + 3] = sp(0.f) - dx;
        }
    }

    // ---- stage D: even outputs (bins r+16*k2) + paired logs ----
    const float HALF_LN2 = 0.34657359027997264f; // v_log_f32 is log2
    v2f m2[8];
#pragma unroll
    for (int t = 0; t < 8; ++t) {
        const v2f Yx = bbx[2 * t] + bbx[2 * t + 1];
        const v2f Yy = bby[2 * t] + bby[2 * t + 1];
        m2[t] = Yx * Yx + Yy * Yy + sp(1e-14f);
    }
    const v2f P0 = m2[0] * m2[1], P1 = m2[2] * m2[3], P2 = m2[4] * m2[5], P3 = m2[6] * m2[7];
    const float lA = __builtin_amdgcn_logf(P0.x) + __builtin_amdgcn_logf(P1.x)
                   + __builtin_amdgcn_logf(P2.x) + __builtin_amdgcn_logf(P3.x);
    const float lB = __builtin_amdgcn_logf(P0.y) + __builtin_amdgcn_logf(P1.y)
                   + __builtin_amdgcn_logf(P2.y) + __builtin_amdgcn_logf(P3.y);
    v2f ssum = sp(HALF_LN2) * mk2(lA, lB) + sp(aw8r);

    // ---- bin 128 from lane 0's odd FFT output: Y[8] = pos0 - pos1 (real) ----
    const v2f d0 = bbx[0] - bbx[1];
    if (r == 0) {
        ssum += sp(HALF_LN2) * mk2(__builtin_amdgcn_logf(d0.x * d0.x + 1e-14f),
                                   __builtin_amdgcn_logf(d0.y * d0.y + 1e-14f))
              + sp(aw128);
    }

    // ---- reduce across the 16 lanes of this group (DPP, no LDS) ----
    ssum.x = rsum16(ssum.x);
    ssum.y = rsum16(ssum.y);

    if (r == 0) {
        out[b * N_FRAMES + fA] = ssum.x * (1.0f / 129.0f);
        out[b * N_FRAMES + fB] = ssum.y * (1.0f / 129.0f);
    }
}

extern "C" void kernel_launch(void* const* d_in, const int* in_sizes, int n_in,
                              void* d_out, int out_size, void* d_ws, size_t ws_size,
                              hipStream_t stream) {
    const float* x = (const float*)d_in[0];
    float* out = (float*)d_out;
    float* ws = (float*)d_ws;
    setup_kernel<<<1, 256, 0, stream>>>(ws);
    loudness_kernel<<<(NB * N_PAIRS) / GPB, 256, 0, stream>>>(x, out, ws);
}

// Round 15
// 55.177 us; speedup vs baseline: 1.0405x; 1.0405x over previous
//
#include <hip/hip_runtime.h>
#include <math.h>

#define HOP 128
#define T_LEN 640000
#define N_FRAMES 5001
#define N_PAIRS 2501
#define NB 64
#define GPB 16            // pair-groups per block; 16 threads per group

// LDS geometry (v2f units). 2*GRP mod 32 == 8 -> groups rotate 8 banks.
#define RE_SLOT 18
#define RE_GRP  164       // 9 slots, span 8*18+16=160, pad to 164 (164%16==4)
#define IM_SLOT 18
#define IM_GRP  132       // 7 slots (k=1..7), span 6*18+16=124, pad to 132

typedef float v2f __attribute__((ext_vector_type(2)));

static __device__ __forceinline__ v2f mk2(float a, float b) { v2f r; r.x = a; r.y = b; return r; }
static __device__ __forceinline__ v2f sp(float s) { v2f r; r.x = s; r.y = s; return r; }

// 16-lane sum reduction via DPP (no LDS traffic); groups are 16-lane aligned.
static __device__ __forceinline__ float rsum16(float v) {
    v += __int_as_float(__builtin_amdgcn_update_dpp(0, __float_as_int(v), 0xB1, 0xF, 0xF, true));  // quad_perm [1,0,3,2]
    v += __int_as_float(__builtin_amdgcn_update_dpp(0, __float_as_int(v), 0x4E, 0xF, 0xF, true));  // quad_perm [2,3,0,1]
    v += __int_as_float(__builtin_amdgcn_update_dpp(0, __float_as_int(v), 0x141, 0xF, 0xF, true)); // row_half_mirror
    v += __int_as_float(__builtin_amdgcn_update_dpp(0, __float_as_int(v), 0x140, 0xF, 0xF, true)); // row_mirror
    return v;
}

// ws layout (floats): [0..511] twT as 256 v2f, twT[w*16+r] = (cos,-sin)(2pi*r*w/256)
//                     [512..527] aw8[r] = sum_{k2} aw[r+16*k2]; [528] aw[128]
__global__ __launch_bounds__(256) void setup_kernel(float* __restrict__ ws) {
    __shared__ float s_aw[132];
    const int tid = threadIdx.x;
    const float TP = 0.02454369260617026f; // 2*pi/256
    {
        const int w = tid >> 4, rr = tid & 15;
        float s, c;
        sincosf((float)(rr * w) * TP, &s, &c);
        ((v2f*)ws)[tid] = mk2(c, -s);
    }
    if (tid < 129) {
        const float LG2_10 = 0.30102999566398f; // log10(x) = log2(x)*this
        float fq = (float)tid * 62.5f;
        float f2 = fq * fq;
        const float a0 = 12194.217f * 12194.217f;
        const float a1 = 20.598997f * 20.598997f;
        const float a2 = 107.65265f * 107.65265f;
        const float a3 = 737.86223f * 737.86223f;
        float w = 2.0f + 20.0f * LG2_10 *
                  (__builtin_amdgcn_logf(a0) + 2.0f * __builtin_amdgcn_logf(fmaxf(f2, 1e-30f))
                 - __builtin_amdgcn_logf(f2 + a0) - __builtin_amdgcn_logf(f2 + a1)
                 - 0.5f * __builtin_amdgcn_logf(f2 + a2) - 0.5f * __builtin_amdgcn_logf(f2 + a3));
        s_aw[tid] = fmaxf(w, -80.0f);
    }
    __syncthreads();
    if (tid < 16) {
        float s = 0.f;
#pragma unroll
        for (int k2 = 0; k2 < 8; ++k2) s += s_aw[tid + 16 * k2];
        ws[512 + tid] = s;
        if (tid == 0) ws[528] = s_aw[128];
    }
}

__global__ __launch_bounds__(256) void loudness_kernel(const float* __restrict__ x,
                                                       float* __restrict__ out,
                                                       const float* __restrict__ ws) {
    constexpr float C16[16] = {
        1.0f,  0.9238795325112867f,  0.7071067811865476f,  0.3826834323650898f,
        0.0f, -0.3826834323650898f, -0.7071067811865476f, -0.9238795325112867f,
       -1.0f, -0.9238795325112867f, -0.7071067811865476f, -0.3826834323650898f,
        0.0f,  0.3826834323650898f,  0.7071067811865476f,  0.9238795325112867f};
    constexpr float S16[16] = {
        0.0f,  0.3826834323650898f,  0.7071067811865476f,  0.9238795325112867f,
        1.0f,  0.9238795325112867f,  0.7071067811865476f,  0.3826834323650898f,
        0.0f, -0.3826834323650898f, -0.7071067811865476f, -0.9238795325112867f,
       -1.0f, -0.9238795325112867f, -0.7071067811865476f, -0.3826834323650898f};
    const float R2  = 0.7071067811865476f;
    const float c1v = 0.9238795325112867f, s1v = 0.3826834323650898f;
    const float c3v = 0.3826834323650898f, s3v = 0.9238795325112867f;
    const float CP8 = 0.9238795325112867f, SP8 = 0.3826834323650898f;
    const float K2  = 1.8477590650225735f; // 2*cos(pi/8)

    __shared__ alignas(16) v2f s_re[16 * RE_GRP];  // 20992 B
    __shared__ alignas(16) v2f s_im[16 * IM_GRP];  // 16896 B
    __shared__ v2f s_twT[256];                     //  2048 B -> 39936 total (4 blk/CU)

    const int tid = threadIdx.x;
    const int g = tid >> 4;   // pair-group in block (4 groups per wave)
    const int r = tid & 15;   // lane role: stage-1 n1; stage-2 k1

    // ---- preamble: copy twiddle table, load per-lane scalars (no trig, no logs) ----
    s_twT[tid] = ((const v2f*)ws)[tid];
    const float aw8r  = ws[512 + r];
    const float aw128 = ws[528];
    const v2f stp = ((const v2f*)ws)[16 + r];   // (cos,-sin)(2pi*r/256)

    // Hann window win(n2) = 0.5 - 0.5*cos(th_r + n2*pi/8), hoisted recurrence
    float win16[16];
    {
        float cm2 = stp.x;
        float cm1 = stp.x * CP8 + stp.y * SP8;  // cos(th + pi/8)  (stp.y = -sin th)
        win16[0] = 0.5f - 0.5f * cm2;
        win16[1] = 0.5f - 0.5f * cm1;
#pragma unroll
        for (int n = 2; n < 16; ++n) {
            const float c = K2 * cm1 - cm2;
            win16[n] = 0.5f - 0.5f * c;
            cm2 = cm1; cm1 = c;
        }
    }
    __syncthreads();  // s_twT visible to all waves (the only barrier)

    const int gp = blockIdx.x * GPB + g;
    const int b  = gp / N_PAIRS;
    const int pp = gp - b * N_PAIRS;
    const int fA = 2 * pp;
    const int fB = (fA < 5000) ? fA + 1 : 5000;  // last pair duplicates frame 5000
    const int dB = (fB - fA) * HOP;              // 128 or 0
    const float* __restrict__ xb = x + (size_t)b * T_LEN;

    // ---- load + window, frames packed (A,B) in v2f ----
    // Interior: dB==128==16*8, so B's sample n2 == A's sample n2+8 (24 loads).
    v2f xw[16];
    const int base = fA * HOP - HOP + r;
    if (pp >= 1 && pp <= 2499) {
        const float* __restrict__ xp = xb + base;
        float s24[24];
#pragma unroll
        for (int j = 0; j < 24; ++j) s24[j] = xp[16 * j];
#pragma unroll
        for (int n2 = 0; n2 < 16; ++n2)
            xw[n2] = mk2(s24[n2], s24[n2 + 8]) * sp(win16[n2]);
    } else {
#pragma unroll
        for (int n2 = 0; n2 < 16; ++n2) {
            int jA = base + 16 * n2;
            int jB = jA + dB;
            jA = (jA < 0) ? -jA : jA;
            jA = (jA >= T_LEN) ? (2 * T_LEN - 2 - jA) : jA;
            jB = (jB < 0) ? -jB : jB;
            jB = (jB >= T_LEN) ? (2 * T_LEN - 2 - jB) : jB;
            xw[n2] = mk2(xb[jA], xb[jB]) * sp(win16[n2]);
        }
    }

    // ---- stage 1: real DFT-16 over n2 (frames packed), Hermitian compact ----
    v2f pv[8], qv[8];
#pragma unroll
    for (int n = 1; n <= 7; ++n) { pv[n] = xw[n] + xw[16 - n]; qv[n] = xw[n] - xw[16 - n]; }
    const v2f bse = xw[0] + xw[8];
    const v2f d08 = xw[0] - xw[8];
    const v2f se  = pv[2] + pv[4] + pv[6];
    const v2f so  = pv[1] + pv[3] + pv[5] + pv[7];
    const v2f r0  = bse + se + so;
    const v2f r8  = bse + se - so;
    v2f rre[8], rim[8];
#pragma unroll
    for (int k1 = 1; k1 <= 7; ++k1) {
        v2f re = (k1 & 1) ? d08 : bse;
        v2f im = sp(0.f);
#pragma unroll
        for (int n = 1; n <= 7; ++n) {
            const int m = (k1 * n) & 15;
            re += pv[n] * sp(C16[m]);
            im -= qv[n] * sp(S16[m]);
        }
        rre[k1] = re;
        rim[k1] = im;
    }

    // ---- write Hermitian-compact spectrum, slot-major (b64, conflict-free) ----
    {
        v2f* __restrict__ reW = &s_re[g * RE_GRP + r];
        v2f* __restrict__ imW = &s_im[g * IM_GRP + r];
        reW[0] = r0;
#pragma unroll
        for (int k = 1; k <= 7; ++k) {
            reW[RE_SLOT * k] = rre[k];
            imW[IM_SLOT * (k - 1)] = rim[k];
        }
        reW[RE_SLOT * 8] = r8;
    }
    // groups are intra-wave (16 lanes within one wave64): no barrier needed,
    // compiler inserts lgkmcnt for the LDS RAW hazard.

    // ---- read column (transpose, b128 = two w's) + table twiddles ----
    const int rp  = (r <= 8) ? r : 16 - r;
    const int rpi = (rp >= 1 && rp <= 7) ? (rp - 1) : 0;           // im slot (k-1)
    const float ysgn = (r == 0 || r == 8) ? 0.f : ((r < 8) ? 1.f : -1.f); // 0 kills garbage
    const float4* __restrict__ reCol = (const float4*)&s_re[g * RE_GRP + RE_SLOT * rp];
    const float4* __restrict__ imCol = (const float4*)&s_im[g * IM_GRP + IM_SLOT * rpi];
    const v2f* __restrict__ twp = &s_twT[r];   // twp[16*w] = tw(r,w), base 8r + imm 128w

    v2f bbx[16], bby[16];
#pragma unroll
    for (int j = 0; j < 8; ++j) {
        const float4 R4v = reCol[j];
        const float4 I4v = imCol[j];
        {
            const int w = 2 * j;
            const v2f tw = twp[16 * w];
            const v2f xx = mk2(R4v.x, R4v.y);
            const v2f yy = mk2(I4v.x, I4v.y) * sp(ysgn);
            bbx[w] = xx * sp(tw.x) - yy * sp(tw.y);
            bby[w] = xx * sp(tw.y) + yy * sp(tw.x);
        }
        {
            const int w = 2 * j + 1;
            const v2f tw = twp[16 * w];
            const v2f xx = mk2(R4v.z, R4v.w);
            const v2f yy = mk2(I4v.z, I4v.w) * sp(ysgn);
            bbx[w] = xx * sp(tw.x) - yy * sp(tw.y);
            bby[w] = xx * sp(tw.y) + yy * sp(tw.x);
        }
    }

    // ---- stage 2: radix-2 DIF FFT-16 over w ----
#pragma unroll
    for (int j = 0; j < 8; ++j) {
        const v2f ux = bbx[j], uy = bby[j], vx = bbx[j + 8], vy = bby[j + 8];
        bbx[j] = ux + vx; bby[j] = uy + vy;
        const v2f dx = ux - vx, dy = uy - vy;
        v2f ox, oy;
        if      (j == 0) { ox = dx;                              oy = dy; }
        else if (j == 1) { ox =  dx * sp(c1v) + dy * sp(s1v);    oy =  dy * sp(c1v) - dx * sp(s1v); }
        else if (j == 2) { ox = (dx + dy) * sp(R2);              oy = (dy - dx) * sp(R2); }
        else if (j == 3) { ox =  dx * sp(c3v) + dy * sp(s3v);    oy =  dy * sp(c3v) - dx * sp(s3v); }
        else if (j == 4) { ox = dy;                              oy = sp(0.f) - dx; }
        else if (j == 5) { ox = dy * sp(s3v) - dx * sp(c3v);     oy = sp(0.f) - dy * sp(c3v) - dx * sp(s3v); }
        else if (j == 6) { ox = (dy - dx) * sp(R2);              oy = sp(0.f) - (dx + dy) * sp(R2); }
        else             { ox = dy * sp(s1v) - dx * sp(c1v);     oy = sp(0.f) - dy * sp(c1v) - dx * sp(s1v); }
        bbx[j + 8] = ox; bby[j + 8] = oy;
    }
#pragma unroll
    for (int h = 0; h <= 8; h += 8) {
#pragma unroll
        for (int j = 0; j < 4; ++j) {
            const v2f ux = bbx[h + j], uy = bby[h + j], vx = bbx[h + j + 4], vy = bby[h + j + 4];
            bbx[h + j] = ux + vx; bby[h + j] = uy + vy;
            const v2f dx = ux - vx, dy = uy - vy;
            v2f ox, oy;
            if      (j == 0) { ox = dx;                  oy = dy; }
            else if (j == 1) { ox = (dx + dy) * sp(R2);  oy = (dy - dx) * sp(R2); }
            else if (j == 2) { ox = dy;                  oy = sp(0.f) - dx; }
            else             { ox = (dy - dx) * sp(R2);  oy = sp(0.f) - (dx + dy) * sp(R2); }
            bbx[h + j + 4] = ox; bby[h + j + 4] = oy;
        }
    }
#pragma unroll
    for (int gg = 0; gg < 16; gg += 4) {
        {
            const v2f ux = bbx[gg], uy = bby[gg], vx = bbx[gg + 2], vy = bby[gg + 2];
            bbx[gg] = ux + vx;     bby[gg] = uy + vy;
            bbx[gg + 2] = ux - vx; bby[gg + 2] = uy - vy;
        }
        {
            const v2f ux = bbx[gg + 1], uy = bby[gg + 1], vx = bbx[gg + 3], vy = bby[gg + 3];
            bbx[gg + 1] = ux + vx; bby[gg + 1] = uy + vy;
            const v2f dx = ux - vx, dy = uy - vy;
            bbx[gg + 3] = dy; bby[gg + 3] = sp(0.f) - dx;
        }
    }

    // ---- stage D: even outputs (bins r+16*k2) + paired logs ----
    const float HALF_LN2 = 0.34657359027997264f; // v_log_f32 is log2
    v2f m2[8];
#pragma unroll
    for (int t = 0; t < 8; ++t) {
        const v2f Yx = bbx[2 * t] + bbx[2 * t + 1];
        const v2f Yy = bby[2 * t] + bby[2 * t + 1];
        m2[t] = Yx * Yx + Yy * Yy + sp(1e-14f);
    }
    const v2f P0 = m2[0] * m2[1], P1 = m2[2] * m2[3], P2 = m2[4] * m2[5], P3 = m2[6] * m2[7];
    const float lA = __builtin_amdgcn_logf(P0.x) + __builtin_amdgcn_logf(P1.x)
                   + __builtin_amdgcn_logf(P2.x) + __builtin_amdgcn_logf(P3.x);
    const float lB = __builtin_amdgcn_logf(P0.y) + __builtin_amdgcn_logf(P1.y)
                   + __builtin_amdgcn_logf(P2.y) + __builtin_amdgcn_logf(P3.y);
    v2f ssum = sp(HALF_LN2) * mk2(lA, lB) + sp(aw8r);

    // ---- bin 128 from lane 0's odd FFT output: Y[8] = pos0 - pos1 (real) ----
    const v2f d0 = bbx[0] - bbx[1];
    if (r == 0) {
        ssum += sp(HALF_LN2) * mk2(__builtin_amdgcn_logf(d0.x * d0.x + 1e-14f),
                                   __builtin_amdgcn_logf(d0.y * d0.y + 1e-14f))
              + sp(aw128);
    }

    // ---- reduce across the 16 lanes of this group (DPP, no LDS) ----
    ssum.x = rsum16(ssum.x);
    ssum.y = rsum16(ssum.y);

    if (r == 0) {
        out[b * N_FRAMES + fA] = ssum.x * (1.0f / 129.0f);
        out[b * N_FRAMES + fB] = ssum.y * (1.0f / 129.0f);
    }
}

extern "C" void kernel_launch(void* const* d_in, const int* in_sizes, int n_in,
                              void* d_out, int out_size, void* d_ws, size_t ws_size,
                              hipStream_t stream) {
    const float* x = (const float*)d_in[0];
    float* out = (float*)d_out;
    float* ws = (float*)d_ws;
    setup_kernel<<<1, 256, 0, stream>>>(ws);
    loudness_kernel<<<(NB * N_PAIRS) / GPB, 256, 0, stream>>>(x, out, ws);
}